// Round 13
// baseline (586.017 us; speedup 1.0000x reference)
//
#include <hip/hip_runtime.h>

#define N_NODES 50000
#define N_EDGES 600000
#define D 128
#define NLAYERS 5
#define EPS 1e-5f
#define MT 32                                   // fused_mlp row tile
#define GX_BLOCKS ((N_NODES + MT - 1) / MT)     // 1563
#define NSLOT 16                                // stats accumulation slots

typedef _Float16 f16;
typedef f16 f16x8 __attribute__((ext_vector_type(8)));
typedef f16 f16x4 __attribute__((ext_vector_type(4)));
typedef float f32x4 __attribute__((ext_vector_type(4)));

// ---------------- CSR build ----------------

__global__ void deg_kernel(const int* __restrict__ dst, int* __restrict__ deg) {
    int e = blockIdx.x * blockDim.x + threadIdx.x;
    if (e < N_EDGES) atomicAdd(&deg[dst[e]], 1);
}

// per-block exclusive scan; blocksums[b] = block total
__global__ __launch_bounds__(1024) void scan_block_kernel(const int* __restrict__ deg,
                                                          int* __restrict__ offsets,
                                                          int* __restrict__ blocksums) {
    __shared__ int tmp[1024];
    int i = blockIdx.x * 1024 + threadIdx.x;
    int v = (i < N_NODES) ? deg[i] : 0;
    tmp[threadIdx.x] = v;
    __syncthreads();
#pragma unroll
    for (int off = 1; off < 1024; off <<= 1) {
        int t = (threadIdx.x >= off) ? tmp[threadIdx.x - off] : 0;
        __syncthreads();
        tmp[threadIdx.x] += t;
        __syncthreads();
    }
    if (i < N_NODES) offsets[i] = tmp[threadIdx.x] - v;  // exclusive
    if (threadIdx.x == 1023) blocksums[blockIdx.x] = tmp[1023];
}

// adds cross-block prefix (computed per block from blocksums), inits cursor, caps offsets
__global__ __launch_bounds__(1024) void scan_add_kernel(int* __restrict__ offsets,
                                                        const int* __restrict__ blocksums,
                                                        int* __restrict__ cursor) {
    __shared__ int base_s;
    if (threadIdx.x == 0) {
        int s = 0;
        for (int r = 0; r < blockIdx.x; ++r) s += blocksums[r];
        base_s = s;
    }
    __syncthreads();
    int i = blockIdx.x * 1024 + threadIdx.x;
    if (i < N_NODES) {
        int v = offsets[i] + base_s;
        offsets[i] = v;
        cursor[i] = v;
        if (i == N_NODES - 1) offsets[N_NODES] = N_EDGES;
    }
}

__global__ void scatter_kernel(const int* __restrict__ src, const int* __restrict__ dst,
                               int* __restrict__ cursor, int* __restrict__ sorted_src) {
    int e = blockIdx.x * blockDim.x + threadIdx.x;
    if (e >= N_EDGES) return;
    int t = dst[e];
    int pos = atomicAdd(&cursor[t], 1);
    sorted_src[pos] = src[e];
}

// ---------------- weight/emb convert ----------------
// w1f: per layer [cb=16][kk=4][lane=64][e=8];  n = cb*16+(lane&15), k = kk*32+(lane>>4)*8+e
// w2f: per layer [cb=8 ][kk=8][lane=64][e=8];  n = cb*16+(lane&15), k = kk*32+(lane>>4)*8+e
__global__ void convert_w_kernel(const float* __restrict__ W1, const float* __restrict__ W2,
                                 const float* __restrict__ emb,
                                 f16* __restrict__ w1f, f16* __restrict__ w2f,
                                 f16* __restrict__ emb_h) {
    int idx = blockIdx.x * blockDim.x + threadIdx.x;
    if (idx >= NLAYERS * 32768) return;
    if (idx < 5 * D) emb_h[idx] = (f16)emb[idx];
    int l = idx >> 15, rem = idx & 32767;
    {
        int e = rem & 7, lane = (rem >> 3) & 63, kk = (rem >> 9) & 3, cb = rem >> 11;
        int n = cb * 16 + (lane & 15);
        int k = kk * 32 + (lane >> 4) * 8 + e;
        w1f[idx] = (f16)W1[((size_t)l * D + k) * (2 * D) + n];
    }
    {
        int e = rem & 7, lane = (rem >> 3) & 63, kk = (rem >> 9) & 7, cb = rem >> 12;
        int n = cb * 16 + (lane & 15);
        int k = kk * 32 + (lane >> 4) * 8 + e;
        w2f[idx] = (f16)W2[((size_t)l * 2 * D + k) * D + n];
    }
}

// ---------------- model kernels ----------------

// pull aggregation with fused producer transform; fp32 accumulate, f16 output.
// MODE 0: source row s = emb_h[x[s]]                 (layer 0)
// MODE 1: source row s = relu(scale*z_prev[s]+shift) (BN+relu of prev layer fused)
// One wave per node; 4 groups x 16 lanes; contiguous per-group edge split with
// batches of 4 independent row loads.
template <int MODE>
__global__ __launch_bounds__(256) void agg_kernel(const int* __restrict__ offsets,
                                                  const int* __restrict__ sorted_src,
                                                  const f16* __restrict__ hprev,
                                                  const int* __restrict__ x,
                                                  const float* __restrict__ ss,
                                                  f16* __restrict__ agg_h) {
    int node = blockIdx.x * 4 + (threadIdx.x >> 6);
    if (node >= N_NODES) return;
    const int lane = threadIdx.x & 63;
    const int g = lane >> 4;   // edge subgroup 0..3
    const int c = lane & 15;   // 8-elem chunk of the row

    float scale[8], shift[8];
    if constexpr (MODE == 1) {
        *(float4*)&scale[0] = *(const float4*)(ss + c * 8);
        *(float4*)&scale[4] = *(const float4*)(ss + c * 8 + 4);
        *(float4*)&shift[0] = *(const float4*)(ss + 128 + c * 8);
        *(float4*)&shift[4] = *(const float4*)(ss + 128 + c * 8 + 4);
    }

    const int begin = offsets[node], end = offsets[node + 1];
    const int deg = end - begin;
    const int lo = begin + ((deg * g) >> 2);
    const int hi = begin + ((deg * (g + 1)) >> 2);

    float acc[8];
    if (g == 0) {  // self loop, counted once
        const f16* srow = (MODE == 0) ? (hprev + (size_t)x[node] * D)
                                      : (hprev + (size_t)node * D);
        f16x8 v = *(const f16x8*)(srow + c * 8);
        if constexpr (MODE == 0) {
#pragma unroll
            for (int k = 0; k < 8; ++k) acc[k] = (float)v[k];
        } else {
#pragma unroll
            for (int k = 0; k < 8; ++k) acc[k] = fmaxf(scale[k] * (float)v[k] + shift[k], 0.f);
        }
    } else {
#pragma unroll
        for (int k = 0; k < 8; ++k) acc[k] = 0.f;
    }

    for (int j = lo; j < hi; j += 4) {
        const int n = hi - j;
        int s0 = sorted_src[j];
        int s1 = (n > 1) ? sorted_src[j + 1] : s0;
        int s2 = (n > 2) ? sorted_src[j + 2] : s0;
        int s3 = (n > 3) ? sorted_src[j + 3] : s0;
        if constexpr (MODE == 0) {
            s0 = x[s0]; s1 = x[s1]; s2 = x[s2]; s3 = x[s3];
        }
        f16x8 v0 = *(const f16x8*)(hprev + (size_t)s0 * D + c * 8);
        f16x8 v1 = *(const f16x8*)(hprev + (size_t)s1 * D + c * 8);
        f16x8 v2 = *(const f16x8*)(hprev + (size_t)s2 * D + c * 8);
        f16x8 v3 = *(const f16x8*)(hprev + (size_t)s3 * D + c * 8);
        if constexpr (MODE == 0) {
#pragma unroll
            for (int k = 0; k < 8; ++k) {
                float a = (float)v0[k];
                if (n > 1) a += (float)v1[k];
                if (n > 2) a += (float)v2[k];
                if (n > 3) a += (float)v3[k];
                acc[k] += a;
            }
        } else {
#pragma unroll
            for (int k = 0; k < 8; ++k) {
                float a = fmaxf(scale[k] * (float)v0[k] + shift[k], 0.f);
                if (n > 1) a += fmaxf(scale[k] * (float)v1[k] + shift[k], 0.f);
                if (n > 2) a += fmaxf(scale[k] * (float)v2[k] + shift[k], 0.f);
                if (n > 3) a += fmaxf(scale[k] * (float)v3[k] + shift[k], 0.f);
                acc[k] += a;
            }
        }
    }

    // sum the 4 groups (lanes sharing c)
#pragma unroll
    for (int k = 0; k < 8; ++k) {
        acc[k] += __shfl_xor(acc[k], 16, 64);
        acc[k] += __shfl_xor(acc[k], 32, 64);
    }
    if (g == 0) {
        f16x8 o;
#pragma unroll
        for (int k = 0; k < 8; ++k) o[k] = (f16)acc[k];
        *(f16x8*)(agg_h + (size_t)node * D + c * 8) = o;
    }
}

__device__ __forceinline__ void gload_lds16(const void* g, void* l) {
    __builtin_amdgcn_global_load_lds((const __attribute__((address_space(1))) void*)g,
                                     (__attribute__((address_space(3))) void*)l, 16, 0, 0);
}

// Fused GIN MLP, 32-row tile: z2 = (relu(agg @ W1 + b1)) @ W2 + b2 (f16).
// Column stats accumulate via global atomicAdd into partial2[blockIdx&15][256].
// The LAST block (device-wide ticket) drains the slots (atomicExch read+zero),
// computes BN affine ss[] and resets the ticket — no separate reduce kernel.
__global__ __launch_bounds__(256) void fused_mlp(const f16* __restrict__ A,
                                                 const f16* __restrict__ w1f,
                                                 const float* __restrict__ b1,
                                                 const f16* __restrict__ w2f,
                                                 const float* __restrict__ b2,
                                                 const float* __restrict__ gamma,
                                                 const float* __restrict__ beta,
                                                 f16* __restrict__ z2h,
                                                 float* __restrict__ partial2,
                                                 int* __restrict__ counter,
                                                 float* __restrict__ ss) {
    __shared__ __align__(16) char smem[16384];
    f16* As = (f16*)smem;                   // 32 x 128 halfs, swizzled (8 KB), aliased by z1s
    f16* z1s = (f16*)smem;                  // 32 x 256 halfs, swizzled (16 KB)

    const int tid = threadIdx.x;
    const int r0 = blockIdx.x * MT;
    const int lane = tid & 63;
    const int wave = tid >> 6;
    const int wr = wave >> 1, wc = wave & 1;
    const int l15 = lane & 15, l4 = lane >> 4;

    // ---- stage A tile (32 x 128): linear LDS dest + pre-swizzled global source ----
#pragma unroll
    for (int it = 0; it < 2; ++it) {
        const int idx = it * 256 + tid;
        const int row = idx >> 4, c = idx & 15;
        const char* gsrc = (const char*)(A + (size_t)(r0 + row) * D) + ((c * 16) ^ ((row & 7) << 4));
        gload_lds16(gsrc, (char*)As + idx * 16);
    }
    __syncthreads();

    // ---- stage 1: z1^T via mfma(W1, A). lane holds z1[m=l15][n=cf*16+l4*4+j] ----
    f32x4 acc1[8] = {};
#pragma unroll
    for (int kk = 0; kk < 4; ++kk) {
        const int m = wr * 16 + l15;
        const int byte = ((m * D + kk * 32 + l4 * 8) * 2) ^ ((m & 7) << 4);
        f16x8 afr = *(const f16x8*)((const char*)As + byte);
#pragma unroll
        for (int cf = 0; cf < 8; ++cf) {
            f16x8 w = *(const f16x8*)(w1f + ((((wc * 8 + cf) * 4) + kk) * 64 + lane) * 8);
            acc1[cf] = __builtin_amdgcn_mfma_f32_16x16x32_f16(w, afr, acc1[cf], 0, 0, 0);
        }
    }
    __syncthreads();  // all As reads complete before overwriting with z1s

    // ---- epilogue 1: bias + relu -> f16 -> z1s (contiguous 8B writes, swizzled) ----
    {
        const int m = wr * 16 + l15;
#pragma unroll
        for (int cf = 0; cf < 8; ++cf) {
            const int n = wc * 128 + cf * 16 + l4 * 4;
            const float4 bb = *(const float4*)(b1 + n);
            f16x4 v;
            v[0] = (f16)fmaxf(acc1[cf][0] + bb.x, 0.f);
            v[1] = (f16)fmaxf(acc1[cf][1] + bb.y, 0.f);
            v[2] = (f16)fmaxf(acc1[cf][2] + bb.z, 0.f);
            v[3] = (f16)fmaxf(acc1[cf][3] + bb.w, 0.f);
            const int byte = ((m * 256 + n) * 2) ^ ((m & 7) << 4);
            *(f16x4*)((char*)z1s + byte) = v;
        }
    }
    __syncthreads();

    // ---- stage 2: z2 = z1 @ W2 (non-swapped), 4 col frags per wave ----
    f32x4 acc2[4] = {};
#pragma unroll
    for (int kk = 0; kk < 8; ++kk) {
        const int m = wr * 16 + l15;
        const int byte = ((m * 256 + kk * 32 + l4 * 8) * 2) ^ ((m & 7) << 4);
        f16x8 afr = *(const f16x8*)((const char*)z1s + byte);
#pragma unroll
        for (int cf = 0; cf < 4; ++cf) {
            f16x8 w = *(const f16x8*)(w2f + ((((wc * 4 + cf) * 8) + kk) * 64 + lane) * 8);
            acc2[cf] = __builtin_amdgcn_mfma_f32_16x16x32_f16(afr, w, acc2[cf], 0, 0, 0);
        }
    }

    // ---- epilogue 2: bias, store f16, column stats direct to global slot ----
    float bv[4];
#pragma unroll
    for (int cf = 0; cf < 4; ++cf) bv[cf] = b2[wc * 64 + cf * 16 + l15];

    float* slot = partial2 + (size_t)(blockIdx.x & (NSLOT - 1)) * 256;
    float cs[4], cq[4];
#pragma unroll
    for (int cf = 0; cf < 4; ++cf) { cs[cf] = 0.f; cq[cf] = 0.f; }
#pragma unroll
    for (int cf = 0; cf < 4; ++cf) {
        const int col = wc * 64 + cf * 16 + l15;
#pragma unroll
        for (int j = 0; j < 4; ++j) {
            const int row = r0 + wr * 16 + l4 * 4 + j;
            if (row < N_NODES) {
                float z = acc2[cf][j] + bv[cf];
                z2h[(size_t)row * D + col] = (f16)z;
                cs[cf] += z;
                cq[cf] += z * z;
            }
        }
    }
#pragma unroll
    for (int cf = 0; cf < 4; ++cf) {
        float s = cs[cf], q = cq[cf];
        s += __shfl_xor(s, 16, 64);
        q += __shfl_xor(q, 16, 64);
        s += __shfl_xor(s, 32, 64);
        q += __shfl_xor(q, 32, 64);
        if (l4 == 0) {
            const int col = wc * 64 + cf * 16 + l15;
            atomicAdd(&slot[col], s);
            atomicAdd(&slot[D + col], q);
        }
    }

    // ---- device-wide ticket; last block finishes the BN stats ----
    __shared__ int winner;
    __syncthreads();
    if (tid == 0) {
        __threadfence();  // release our slot adds
        winner = (atomicAdd(counter, 1) == GX_BLOCKS - 1) ? 1 : 0;
    }
    __syncthreads();
    if (winner) {
        __threadfence();  // acquire all blocks' slot adds
        float* st = (float*)smem;  // 256 f32 (LDS free by now)
        float s = 0.f;
#pragma unroll
        for (int r = 0; r < NSLOT; ++r)
            s += atomicExch(&partial2[(size_t)r * 256 + tid], 0.f);  // read + zero, coherent
        st[tid] = s;
        __syncthreads();
        if (tid < 128) {
            const float invN = 1.0f / (float)N_NODES;
            float mean = st[tid] * invN;
            float var = st[128 + tid] * invN - mean * mean;
            float sc = gamma[tid] * rsqrtf(var + EPS);
            ss[tid] = sc;                      // visible next kernel (boundary flush)
            ss[128 + tid] = beta[tid] - mean * sc;
        }
        if (tid == 0) *counter = 0;            // reset for next layer / replay
    }
}

// final-layer BN (no relu), f32 output to d_out
__global__ void bn_last_kernel(const f16* __restrict__ z, const float* __restrict__ ss,
                               float* __restrict__ hout) {
    int idx = blockIdx.x * blockDim.x + threadIdx.x;  // one 8-elem chunk
    if (idx >= N_NODES * (D / 8)) return;
    int d8 = idx & 15;
    f16x8 v = *(const f16x8*)(z + (size_t)idx * 8);
    float4 s0 = *(const float4*)(ss + d8 * 8);
    float4 s1 = *(const float4*)(ss + d8 * 8 + 4);
    float4 t0 = *(const float4*)(ss + 128 + d8 * 8);
    float4 t1 = *(const float4*)(ss + 128 + d8 * 8 + 4);
    float4 o0, o1;
    o0.x = s0.x * (float)v[0] + t0.x;
    o0.y = s0.y * (float)v[1] + t0.y;
    o0.z = s0.z * (float)v[2] + t0.z;
    o0.w = s0.w * (float)v[3] + t0.w;
    o1.x = s1.x * (float)v[4] + t1.x;
    o1.y = s1.y * (float)v[5] + t1.y;
    o1.z = s1.z * (float)v[6] + t1.z;
    o1.w = s1.w * (float)v[7] + t1.w;
    *(float4*)(hout + (size_t)idx * 8) = o0;
    *(float4*)(hout + (size_t)idx * 8 + 4) = o1;
}

extern "C" void kernel_launch(void* const* d_in, const int* in_sizes, int n_in,
                              void* d_out, int out_size, void* d_ws, size_t ws_size,
                              hipStream_t stream) {
    const int* x_nodes = (const int*)d_in[0];
    const int* src = (const int*)d_in[1];
    const int* dst = (const int*)d_in[2];
    const float* emb = (const float*)d_in[3];
    const float* W1 = (const float*)d_in[4];
    const float* b1 = (const float*)d_in[5];
    const float* W2 = (const float*)d_in[6];
    const float* b2 = (const float*)d_in[7];
    const float* gamma = (const float*)d_in[8];
    const float* beta = (const float*)d_in[9];

    float* h = (float*)d_out;  // final fp32 output

    // workspace layout: partial2, counter, deg contiguous -> ONE memset covers all
    f16* zA = (f16*)d_ws;                                       // N*D f16 (agg_h)
    f16* zB = zA + (size_t)N_NODES * D;                         // N*D f16 (z2h)
    f16* w1f = zB + (size_t)N_NODES * D;                        // L*32768 f16
    f16* w2f = w1f + (size_t)NLAYERS * 2 * D * D;               // L*32768 f16
    f16* emb_h = w2f + (size_t)NLAYERS * 2 * D * D;             // 5*D f16 (pad to 1024)
    float* ss = (float*)(emb_h + 1024);                         // 256 f32 (scale|shift)
    float* partial2 = ss + 256;                                 // NSLOT*256 f32 (zeroed)
    int* counter = (int*)(partial2 + (size_t)NSLOT * 256);      // 4 ints (zeroed)
    int* deg = counter + 4;                                     // N (zeroed)
    int* offsets = deg + N_NODES;                               // N+1
    int* cursor = offsets + N_NODES + 1;                        // N
    int* blocksums = cursor + N_NODES;                          // 64
    int* sorted_src = blocksums + 64;                           // E

    dim3 blk(256);
    const int nb_scan = (N_NODES + 1023) / 1024;  // 49
    const int nb_edge = (N_EDGES + 255) / 256;

    // ---- one-time per call: weights + CSR ----
    convert_w_kernel<<<(NLAYERS * 32768 + 255) / 256, blk, 0, stream>>>(W1, W2, emb,
                                                                        w1f, w2f, emb_h);
    hipMemsetAsync(partial2, 0,
                   NSLOT * 256 * sizeof(float) + 4 * sizeof(int) + N_NODES * sizeof(int),
                   stream);
    deg_kernel<<<nb_edge, blk, 0, stream>>>(dst, deg);
    scan_block_kernel<<<nb_scan, 1024, 0, stream>>>(deg, offsets, blocksums);
    scan_add_kernel<<<nb_scan, 1024, 0, stream>>>(offsets, blocksums, cursor);
    scatter_kernel<<<nb_edge, blk, 0, stream>>>(src, dst, cursor, sorted_src);

    // ---- model: per layer {agg (fused BN+relu of prev), MLP(+stats+last-block finish)} ----
    const int agg_gx = (N_NODES + 3) / 4;
    for (int l = 0; l < NLAYERS; ++l) {
        if (l == 0) {
            agg_kernel<0><<<agg_gx, blk, 0, stream>>>(offsets, sorted_src, emb_h,
                                                      x_nodes, nullptr, zA);
        } else {
            agg_kernel<1><<<agg_gx, blk, 0, stream>>>(offsets, sorted_src, zB,
                                                      nullptr, ss, zA);
        }
        fused_mlp<<<GX_BLOCKS, blk, 0, stream>>>(zA, w1f + (size_t)l * 32768, b1 + l * 2 * D,
                                                 w2f + (size_t)l * 32768, b2 + l * D,
                                                 gamma + l * D, beta + l * D,
                                                 zB, partial2, counter, ss);
    }
    bn_last_kernel<<<(N_NODES * 16 + 255) / 256, blk, 0, stream>>>(zB, ss, h);
    (void)in_sizes; (void)n_in; (void)out_size; (void)ws_size;
}

// Round 14
// 367.568 us; speedup vs baseline: 1.5943x; 1.5943x over previous
//
#include <hip/hip_runtime.h>

#define N_NODES 50000
#define N_EDGES 600000
#define D 128
#define NLAYERS 5
#define EPS 1e-5f
#define MT 32                                   // fused_mlp row tile
#define GX_BLOCKS ((N_NODES + MT - 1) / MT)     // 1563
#define NSLOT 16                                // stats accumulation slots

typedef _Float16 f16;
typedef f16 f16x8 __attribute__((ext_vector_type(8)));
typedef f16 f16x4 __attribute__((ext_vector_type(4)));
typedef float f32x4 __attribute__((ext_vector_type(4)));

// ---------------- CSR build ----------------

__global__ void deg_kernel(const int* __restrict__ dst, int* __restrict__ deg) {
    int e = blockIdx.x * blockDim.x + threadIdx.x;
    if (e < N_EDGES) atomicAdd(&deg[dst[e]], 1);
}

// per-block exclusive scan; blocksums[b] = block total
__global__ __launch_bounds__(1024) void scan_block_kernel(const int* __restrict__ deg,
                                                          int* __restrict__ offsets,
                                                          int* __restrict__ blocksums) {
    __shared__ int tmp[1024];
    int i = blockIdx.x * 1024 + threadIdx.x;
    int v = (i < N_NODES) ? deg[i] : 0;
    tmp[threadIdx.x] = v;
    __syncthreads();
#pragma unroll
    for (int off = 1; off < 1024; off <<= 1) {
        int t = (threadIdx.x >= off) ? tmp[threadIdx.x - off] : 0;
        __syncthreads();
        tmp[threadIdx.x] += t;
        __syncthreads();
    }
    if (i < N_NODES) offsets[i] = tmp[threadIdx.x] - v;  // exclusive
    if (threadIdx.x == 1023) blocksums[blockIdx.x] = tmp[1023];
}

// adds cross-block prefix (computed per block from blocksums), inits cursor, caps offsets
__global__ __launch_bounds__(1024) void scan_add_kernel(int* __restrict__ offsets,
                                                        const int* __restrict__ blocksums,
                                                        int* __restrict__ cursor) {
    __shared__ int base_s;
    if (threadIdx.x == 0) {
        int s = 0;
        for (int r = 0; r < blockIdx.x; ++r) s += blocksums[r];
        base_s = s;
    }
    __syncthreads();
    int i = blockIdx.x * 1024 + threadIdx.x;
    if (i < N_NODES) {
        int v = offsets[i] + base_s;
        offsets[i] = v;
        cursor[i] = v;
        if (i == N_NODES - 1) offsets[N_NODES] = N_EDGES;
    }
}

__global__ void scatter_kernel(const int* __restrict__ src, const int* __restrict__ dst,
                               int* __restrict__ cursor, int* __restrict__ sorted_src) {
    int e = blockIdx.x * blockDim.x + threadIdx.x;
    if (e >= N_EDGES) return;
    int t = dst[e];
    int pos = atomicAdd(&cursor[t], 1);
    sorted_src[pos] = src[e];
}

// ---------------- weight/emb convert ----------------
// w1f: per layer [cb=16][kk=4][lane=64][e=8];  n = cb*16+(lane&15), k = kk*32+(lane>>4)*8+e
// w2f: per layer [cb=8 ][kk=8][lane=64][e=8];  n = cb*16+(lane&15), k = kk*32+(lane>>4)*8+e
__global__ void convert_w_kernel(const float* __restrict__ W1, const float* __restrict__ W2,
                                 const float* __restrict__ emb,
                                 f16* __restrict__ w1f, f16* __restrict__ w2f,
                                 f16* __restrict__ emb_h) {
    int idx = blockIdx.x * blockDim.x + threadIdx.x;
    if (idx >= NLAYERS * 32768) return;
    if (idx < 5 * D) emb_h[idx] = (f16)emb[idx];
    int l = idx >> 15, rem = idx & 32767;
    {
        int e = rem & 7, lane = (rem >> 3) & 63, kk = (rem >> 9) & 3, cb = rem >> 11;
        int n = cb * 16 + (lane & 15);
        int k = kk * 32 + (lane >> 4) * 8 + e;
        w1f[idx] = (f16)W1[((size_t)l * D + k) * (2 * D) + n];
    }
    {
        int e = rem & 7, lane = (rem >> 3) & 63, kk = (rem >> 9) & 7, cb = rem >> 12;
        int n = cb * 16 + (lane & 15);
        int k = kk * 32 + (lane >> 4) * 8 + e;
        w2f[idx] = (f16)W2[((size_t)l * 2 * D + k) * D + n];
    }
}

// ---------------- model kernels ----------------

// pull aggregation with fused producer transform; fp32 accumulate, f16 output.
// MODE 0: source row s = emb_h[x[s]]                 (layer 0)
// MODE 1: source row s = relu(scale*z_prev[s]+shift) (BN+relu of prev layer fused)
// One wave per node; 4 groups x 16 lanes; contiguous per-group edge split with
// batches of 4 independent row loads.
template <int MODE>
__global__ __launch_bounds__(256) void agg_kernel(const int* __restrict__ offsets,
                                                  const int* __restrict__ sorted_src,
                                                  const f16* __restrict__ hprev,
                                                  const int* __restrict__ x,
                                                  const float* __restrict__ ss,
                                                  f16* __restrict__ agg_h) {
    int node = blockIdx.x * 4 + (threadIdx.x >> 6);
    if (node >= N_NODES) return;
    const int lane = threadIdx.x & 63;
    const int g = lane >> 4;   // edge subgroup 0..3
    const int c = lane & 15;   // 8-elem chunk of the row

    float scale[8], shift[8];
    if constexpr (MODE == 1) {
        *(float4*)&scale[0] = *(const float4*)(ss + c * 8);
        *(float4*)&scale[4] = *(const float4*)(ss + c * 8 + 4);
        *(float4*)&shift[0] = *(const float4*)(ss + 128 + c * 8);
        *(float4*)&shift[4] = *(const float4*)(ss + 128 + c * 8 + 4);
    }

    const int begin = offsets[node], end = offsets[node + 1];
    const int deg = end - begin;
    const int lo = begin + ((deg * g) >> 2);
    const int hi = begin + ((deg * (g + 1)) >> 2);

    float acc[8];
    if (g == 0) {  // self loop, counted once
        const f16* srow = (MODE == 0) ? (hprev + (size_t)x[node] * D)
                                      : (hprev + (size_t)node * D);
        f16x8 v = *(const f16x8*)(srow + c * 8);
        if constexpr (MODE == 0) {
#pragma unroll
            for (int k = 0; k < 8; ++k) acc[k] = (float)v[k];
        } else {
#pragma unroll
            for (int k = 0; k < 8; ++k) acc[k] = fmaxf(scale[k] * (float)v[k] + shift[k], 0.f);
        }
    } else {
#pragma unroll
        for (int k = 0; k < 8; ++k) acc[k] = 0.f;
    }

    for (int j = lo; j < hi; j += 4) {
        const int n = hi - j;
        int s0 = sorted_src[j];
        int s1 = (n > 1) ? sorted_src[j + 1] : s0;
        int s2 = (n > 2) ? sorted_src[j + 2] : s0;
        int s3 = (n > 3) ? sorted_src[j + 3] : s0;
        if constexpr (MODE == 0) {
            s0 = x[s0]; s1 = x[s1]; s2 = x[s2]; s3 = x[s3];
        }
        f16x8 v0 = *(const f16x8*)(hprev + (size_t)s0 * D + c * 8);
        f16x8 v1 = *(const f16x8*)(hprev + (size_t)s1 * D + c * 8);
        f16x8 v2 = *(const f16x8*)(hprev + (size_t)s2 * D + c * 8);
        f16x8 v3 = *(const f16x8*)(hprev + (size_t)s3 * D + c * 8);
        if constexpr (MODE == 0) {
#pragma unroll
            for (int k = 0; k < 8; ++k) {
                float a = (float)v0[k];
                if (n > 1) a += (float)v1[k];
                if (n > 2) a += (float)v2[k];
                if (n > 3) a += (float)v3[k];
                acc[k] += a;
            }
        } else {
#pragma unroll
            for (int k = 0; k < 8; ++k) {
                float a = fmaxf(scale[k] * (float)v0[k] + shift[k], 0.f);
                if (n > 1) a += fmaxf(scale[k] * (float)v1[k] + shift[k], 0.f);
                if (n > 2) a += fmaxf(scale[k] * (float)v2[k] + shift[k], 0.f);
                if (n > 3) a += fmaxf(scale[k] * (float)v3[k] + shift[k], 0.f);
                acc[k] += a;
            }
        }
    }

    // sum the 4 groups (lanes sharing c)
#pragma unroll
    for (int k = 0; k < 8; ++k) {
        acc[k] += __shfl_xor(acc[k], 16, 64);
        acc[k] += __shfl_xor(acc[k], 32, 64);
    }
    if (g == 0) {
        f16x8 o;
#pragma unroll
        for (int k = 0; k < 8; ++k) o[k] = (f16)acc[k];
        *(f16x8*)(agg_h + (size_t)node * D + c * 8) = o;
    }
}

__device__ __forceinline__ void gload_lds16(const void* g, void* l) {
    __builtin_amdgcn_global_load_lds((const __attribute__((address_space(1))) void*)g,
                                     (__attribute__((address_space(3))) void*)l, 16, 0, 0);
}

// Fused GIN MLP, 32-row tile: z2 = (relu(agg @ W1 + b1)) @ W2 + b2 (f16).
// Column stats (sum|sumsq) go straight from the wave shuffle-reduce to global
// atomicAdd into partial2[blockIdx&15][256] (~2 adds/address/block, negligible).
__global__ __launch_bounds__(256) void fused_mlp(const f16* __restrict__ A,
                                                 const f16* __restrict__ w1f,
                                                 const float* __restrict__ b1,
                                                 const f16* __restrict__ w2f,
                                                 const float* __restrict__ b2,
                                                 f16* __restrict__ z2h,
                                                 float* __restrict__ partial2) {
    __shared__ __align__(16) char smem[16384];
    f16* As = (f16*)smem;                   // 32 x 128 halfs, swizzled (8 KB), aliased by z1s
    f16* z1s = (f16*)smem;                  // 32 x 256 halfs, swizzled (16 KB)

    const int tid = threadIdx.x;
    const int r0 = blockIdx.x * MT;
    const int lane = tid & 63;
    const int wave = tid >> 6;
    const int wr = wave >> 1, wc = wave & 1;
    const int l15 = lane & 15, l4 = lane >> 4;

    // ---- stage A tile (32 x 128): linear LDS dest + pre-swizzled global source ----
#pragma unroll
    for (int it = 0; it < 2; ++it) {
        const int idx = it * 256 + tid;
        const int row = idx >> 4, c = idx & 15;
        const char* gsrc = (const char*)(A + (size_t)(r0 + row) * D) + ((c * 16) ^ ((row & 7) << 4));
        gload_lds16(gsrc, (char*)As + idx * 16);
    }
    __syncthreads();

    // ---- stage 1: z1^T via mfma(W1, A). lane holds z1[m=l15][n=cf*16+l4*4+j] ----
    f32x4 acc1[8] = {};
#pragma unroll
    for (int kk = 0; kk < 4; ++kk) {
        const int m = wr * 16 + l15;
        const int byte = ((m * D + kk * 32 + l4 * 8) * 2) ^ ((m & 7) << 4);
        f16x8 afr = *(const f16x8*)((const char*)As + byte);
#pragma unroll
        for (int cf = 0; cf < 8; ++cf) {
            f16x8 w = *(const f16x8*)(w1f + ((((wc * 8 + cf) * 4) + kk) * 64 + lane) * 8);
            acc1[cf] = __builtin_amdgcn_mfma_f32_16x16x32_f16(w, afr, acc1[cf], 0, 0, 0);
        }
    }
    __syncthreads();  // all As reads complete before overwriting with z1s

    // ---- epilogue 1: bias + relu -> f16 -> z1s (contiguous 8B writes, swizzled) ----
    {
        const int m = wr * 16 + l15;
#pragma unroll
        for (int cf = 0; cf < 8; ++cf) {
            const int n = wc * 128 + cf * 16 + l4 * 4;
            const float4 bb = *(const float4*)(b1 + n);
            f16x4 v;
            v[0] = (f16)fmaxf(acc1[cf][0] + bb.x, 0.f);
            v[1] = (f16)fmaxf(acc1[cf][1] + bb.y, 0.f);
            v[2] = (f16)fmaxf(acc1[cf][2] + bb.z, 0.f);
            v[3] = (f16)fmaxf(acc1[cf][3] + bb.w, 0.f);
            const int byte = ((m * 256 + n) * 2) ^ ((m & 7) << 4);
            *(f16x4*)((char*)z1s + byte) = v;
        }
    }
    __syncthreads();

    // ---- stage 2: z2 = z1 @ W2 (non-swapped), 4 col frags per wave ----
    f32x4 acc2[4] = {};
#pragma unroll
    for (int kk = 0; kk < 8; ++kk) {
        const int m = wr * 16 + l15;
        const int byte = ((m * 256 + kk * 32 + l4 * 8) * 2) ^ ((m & 7) << 4);
        f16x8 afr = *(const f16x8*)((const char*)z1s + byte);
#pragma unroll
        for (int cf = 0; cf < 4; ++cf) {
            f16x8 w = *(const f16x8*)(w2f + ((((wc * 4 + cf) * 8) + kk) * 64 + lane) * 8);
            acc2[cf] = __builtin_amdgcn_mfma_f32_16x16x32_f16(afr, w, acc2[cf], 0, 0, 0);
        }
    }

    // ---- epilogue 2: bias, store f16, column stats direct to global slot ----
    float bv[4];
#pragma unroll
    for (int cf = 0; cf < 4; ++cf) bv[cf] = b2[wc * 64 + cf * 16 + l15];

    float* slot = partial2 + (size_t)(blockIdx.x & (NSLOT - 1)) * 256;
    float cs[4], cq[4];
#pragma unroll
    for (int cf = 0; cf < 4; ++cf) { cs[cf] = 0.f; cq[cf] = 0.f; }
#pragma unroll
    for (int cf = 0; cf < 4; ++cf) {
        const int col = wc * 64 + cf * 16 + l15;
#pragma unroll
        for (int j = 0; j < 4; ++j) {
            const int row = r0 + wr * 16 + l4 * 4 + j;
            if (row < N_NODES) {
                float z = acc2[cf][j] + bv[cf];
                z2h[(size_t)row * D + col] = (f16)z;
                cs[cf] += z;
                cq[cf] += z * z;
            }
        }
    }
#pragma unroll
    for (int cf = 0; cf < 4; ++cf) {
        float s = cs[cf], q = cq[cf];
        s += __shfl_xor(s, 16, 64);
        q += __shfl_xor(q, 16, 64);
        s += __shfl_xor(s, 32, 64);
        q += __shfl_xor(q, 32, 64);
        if (l4 == 0) {
            const int col = wc * 64 + cf * 16 + l15;
            atomicAdd(&slot[col], s);
            atomicAdd(&slot[D + col], q);
        }
    }
}

// finish stats from the 16 slots (1024 threads: thread (q,c) sums 4 slots), emit BN
// affine (ss[c]=scale, ss[128+c]=shift), zero the slots behind itself.
__global__ __launch_bounds__(1024) void reduce2_kernel(float* __restrict__ partial2,
                                                       const float* __restrict__ gamma,
                                                       const float* __restrict__ beta,
                                                       float* __restrict__ ss) {
    __shared__ float st[4][256];
    const int c = threadIdx.x & 255, q = threadIdx.x >> 8;
    float s = 0.f;
#pragma unroll
    for (int r = 0; r < 4; ++r) {
        s += partial2[(size_t)(q * 4 + r) * 256 + c];
        partial2[(size_t)(q * 4 + r) * 256 + c] = 0.f;
    }
    st[q][c] = s;
    __syncthreads();
    if (q == 0 && c < 128) {
        float sum = st[0][c] + st[1][c] + st[2][c] + st[3][c];
        float sq = st[0][128 + c] + st[1][128 + c] + st[2][128 + c] + st[3][128 + c];
        const float invN = 1.0f / (float)N_NODES;
        float mean = sum * invN;
        float var = sq * invN - mean * mean;
        float sc = gamma[c] * rsqrtf(var + EPS);
        ss[c] = sc;
        ss[128 + c] = beta[c] - mean * sc;
    }
}

// final-layer BN (no relu), f32 output to d_out
__global__ void bn_last_kernel(const f16* __restrict__ z, const float* __restrict__ ss,
                               float* __restrict__ hout) {
    int idx = blockIdx.x * blockDim.x + threadIdx.x;  // one 8-elem chunk
    if (idx >= N_NODES * (D / 8)) return;
    int d8 = idx & 15;
    f16x8 v = *(const f16x8*)(z + (size_t)idx * 8);
    float4 s0 = *(const float4*)(ss + d8 * 8);
    float4 s1 = *(const float4*)(ss + d8 * 8 + 4);
    float4 t0 = *(const float4*)(ss + 128 + d8 * 8);
    float4 t1 = *(const float4*)(ss + 128 + d8 * 8 + 4);
    float4 o0, o1;
    o0.x = s0.x * (float)v[0] + t0.x;
    o0.y = s0.y * (float)v[1] + t0.y;
    o0.z = s0.z * (float)v[2] + t0.z;
    o0.w = s0.w * (float)v[3] + t0.w;
    o1.x = s1.x * (float)v[4] + t1.x;
    o1.y = s1.y * (float)v[5] + t1.y;
    o1.z = s1.z * (float)v[6] + t1.z;
    o1.w = s1.w * (float)v[7] + t1.w;
    *(float4*)(hout + (size_t)idx * 8) = o0;
    *(float4*)(hout + (size_t)idx * 8 + 4) = o1;
}

extern "C" void kernel_launch(void* const* d_in, const int* in_sizes, int n_in,
                              void* d_out, int out_size, void* d_ws, size_t ws_size,
                              hipStream_t stream) {
    const int* x_nodes = (const int*)d_in[0];
    const int* src = (const int*)d_in[1];
    const int* dst = (const int*)d_in[2];
    const float* emb = (const float*)d_in[3];
    const float* W1 = (const float*)d_in[4];
    const float* b1 = (const float*)d_in[5];
    const float* W2 = (const float*)d_in[6];
    const float* b2 = (const float*)d_in[7];
    const float* gamma = (const float*)d_in[8];
    const float* beta = (const float*)d_in[9];

    float* h = (float*)d_out;  // final fp32 output

    // workspace layout: partial2 and deg contiguous so ONE memset covers both
    f16* zA = (f16*)d_ws;                                       // N*D f16 (agg_h)
    f16* zB = zA + (size_t)N_NODES * D;                         // N*D f16 (z2h)
    f16* w1f = zB + (size_t)N_NODES * D;                        // L*32768 f16
    f16* w2f = w1f + (size_t)NLAYERS * 2 * D * D;               // L*32768 f16
    f16* emb_h = w2f + (size_t)NLAYERS * 2 * D * D;             // 5*D f16 (pad to 1024)
    float* ss = (float*)(emb_h + 1024);                         // 256 f32 (scale|shift)
    float* partial2 = ss + 256;                                 // NSLOT*256 f32 (zeroed)
    int* deg = (int*)(partial2 + (size_t)NSLOT * 256);          // N (zeroed)
    int* offsets = deg + N_NODES;                               // N+1
    int* cursor = offsets + N_NODES + 1;                        // N
    int* blocksums = cursor + N_NODES;                          // 64
    int* sorted_src = blocksums + 64;                           // E

    dim3 blk(256);
    const int nb_scan = (N_NODES + 1023) / 1024;  // 49
    const int nb_edge = (N_EDGES + 255) / 256;

    // ---- one-time per call: weights + CSR ----
    convert_w_kernel<<<(NLAYERS * 32768 + 255) / 256, blk, 0, stream>>>(W1, W2, emb,
                                                                        w1f, w2f, emb_h);
    hipMemsetAsync(partial2, 0, NSLOT * 256 * sizeof(float) + N_NODES * sizeof(int), stream);
    deg_kernel<<<nb_edge, blk, 0, stream>>>(dst, deg);
    scan_block_kernel<<<nb_scan, 1024, 0, stream>>>(deg, offsets, blocksums);
    scan_add_kernel<<<nb_scan, 1024, 0, stream>>>(offsets, blocksums, cursor);
    scatter_kernel<<<nb_edge, blk, 0, stream>>>(src, dst, cursor, sorted_src);

    // ---- model: per layer {agg (fused BN+relu of prev), MLP(+atomic stats), reduce2} ----
    const int agg_gx = (N_NODES + 3) / 4;
    for (int l = 0; l < NLAYERS; ++l) {
        if (l == 0) {
            agg_kernel<0><<<agg_gx, blk, 0, stream>>>(offsets, sorted_src, emb_h,
                                                      x_nodes, nullptr, zA);
        } else {
            agg_kernel<1><<<agg_gx, blk, 0, stream>>>(offsets, sorted_src, zB,
                                                      nullptr, ss, zA);
        }
        fused_mlp<<<GX_BLOCKS, blk, 0, stream>>>(zA, w1f + (size_t)l * 32768, b1 + l * 2 * D,
                                                 w2f + (size_t)l * 32768, b2 + l * D, zB, partial2);
        reduce2_kernel<<<1, 1024, 0, stream>>>(partial2, gamma + l * D, beta + l * D, ss);
    }
    bn_last_kernel<<<(N_NODES * 16 + 255) / 256, blk, 0, stream>>>(zB, ss, h);
    (void)in_sizes; (void)n_in; (void)out_size; (void)ws_size;
}

// Round 15
// 359.064 us; speedup vs baseline: 1.6321x; 1.0237x over previous
//
#include <hip/hip_runtime.h>

#define N_NODES 50000
#define N_EDGES 600000
#define D 128
#define NLAYERS 5
#define EPS 1e-5f
#define MT 16                                   // fused_mlp row tile
#define GX_BLOCKS ((N_NODES + MT - 1) / MT)     // 3125 (exact: 50000 = 16*3125)
#define NSLOT 16                                // stats accumulation slots

typedef _Float16 f16;
typedef f16 f16x8 __attribute__((ext_vector_type(8)));
typedef f16 f16x4 __attribute__((ext_vector_type(4)));
typedef float f32x4 __attribute__((ext_vector_type(4)));

// ---------------- CSR build ----------------

__global__ void deg_kernel(const int* __restrict__ dst, int* __restrict__ deg) {
    int e = blockIdx.x * blockDim.x + threadIdx.x;
    if (e < N_EDGES) atomicAdd(&deg[dst[e]], 1);
}

// per-block exclusive scan; blocksums[b] = block total
__global__ __launch_bounds__(1024) void scan_block_kernel(const int* __restrict__ deg,
                                                          int* __restrict__ offsets,
                                                          int* __restrict__ blocksums) {
    __shared__ int tmp[1024];
    int i = blockIdx.x * 1024 + threadIdx.x;
    int v = (i < N_NODES) ? deg[i] : 0;
    tmp[threadIdx.x] = v;
    __syncthreads();
#pragma unroll
    for (int off = 1; off < 1024; off <<= 1) {
        int t = (threadIdx.x >= off) ? tmp[threadIdx.x - off] : 0;
        __syncthreads();
        tmp[threadIdx.x] += t;
        __syncthreads();
    }
    if (i < N_NODES) offsets[i] = tmp[threadIdx.x] - v;  // exclusive
    if (threadIdx.x == 1023) blocksums[blockIdx.x] = tmp[1023];
}

// adds cross-block prefix (computed per block from blocksums), inits cursor, caps offsets
__global__ __launch_bounds__(1024) void scan_add_kernel(int* __restrict__ offsets,
                                                        const int* __restrict__ blocksums,
                                                        int* __restrict__ cursor) {
    __shared__ int base_s;
    if (threadIdx.x == 0) {
        int s = 0;
        for (int r = 0; r < blockIdx.x; ++r) s += blocksums[r];
        base_s = s;
    }
    __syncthreads();
    int i = blockIdx.x * 1024 + threadIdx.x;
    if (i < N_NODES) {
        int v = offsets[i] + base_s;
        offsets[i] = v;
        cursor[i] = v;
        if (i == N_NODES - 1) offsets[N_NODES] = N_EDGES;
    }
}

__global__ void scatter_kernel(const int* __restrict__ src, const int* __restrict__ dst,
                               int* __restrict__ cursor, int* __restrict__ sorted_src) {
    int e = blockIdx.x * blockDim.x + threadIdx.x;
    if (e >= N_EDGES) return;
    int t = dst[e];
    int pos = atomicAdd(&cursor[t], 1);
    sorted_src[pos] = src[e];
}

// ---------------- weight/emb convert ----------------
// w1f: per layer [cb=16][kk=4][lane=64][e=8];  n = cb*16+(lane&15), k = kk*32+(lane>>4)*8+e
// w2f: per layer [cb=8 ][kk=8][lane=64][e=8];  n = cb*16+(lane&15), k = kk*32+(lane>>4)*8+e
__global__ void convert_w_kernel(const float* __restrict__ W1, const float* __restrict__ W2,
                                 const float* __restrict__ emb,
                                 f16* __restrict__ w1f, f16* __restrict__ w2f,
                                 f16* __restrict__ emb_h) {
    int idx = blockIdx.x * blockDim.x + threadIdx.x;
    if (idx >= NLAYERS * 32768) return;
    if (idx < 5 * D) emb_h[idx] = (f16)emb[idx];
    int l = idx >> 15, rem = idx & 32767;
    {
        int e = rem & 7, lane = (rem >> 3) & 63, kk = (rem >> 9) & 3, cb = rem >> 11;
        int n = cb * 16 + (lane & 15);
        int k = kk * 32 + (lane >> 4) * 8 + e;
        w1f[idx] = (f16)W1[((size_t)l * D + k) * (2 * D) + n];
    }
    {
        int e = rem & 7, lane = (rem >> 3) & 63, kk = (rem >> 9) & 7, cb = rem >> 12;
        int n = cb * 16 + (lane & 15);
        int k = kk * 32 + (lane >> 4) * 8 + e;
        w2f[idx] = (f16)W2[((size_t)l * 2 * D + k) * D + n];
    }
}

// ---------------- model kernels ----------------

// pull aggregation with fused producer transform; fp32 accumulate, f16 output.
// MODE 0: source row s = emb_h[x[s]]                 (layer 0)
// MODE 1: source row s = relu(scale*z_prev[s]+shift) (BN+relu of prev layer fused)
// One wave per node; 4 groups x 16 lanes; contiguous per-group edge split with
// batches of 4 independent row loads.
template <int MODE>
__global__ __launch_bounds__(256) void agg_kernel(const int* __restrict__ offsets,
                                                  const int* __restrict__ sorted_src,
                                                  const f16* __restrict__ hprev,
                                                  const int* __restrict__ x,
                                                  const float* __restrict__ ss,
                                                  f16* __restrict__ agg_h) {
    int node = blockIdx.x * 4 + (threadIdx.x >> 6);
    if (node >= N_NODES) return;
    const int lane = threadIdx.x & 63;
    const int g = lane >> 4;   // edge subgroup 0..3
    const int c = lane & 15;   // 8-elem chunk of the row

    float scale[8], shift[8];
    if constexpr (MODE == 1) {
        *(float4*)&scale[0] = *(const float4*)(ss + c * 8);
        *(float4*)&scale[4] = *(const float4*)(ss + c * 8 + 4);
        *(float4*)&shift[0] = *(const float4*)(ss + 128 + c * 8);
        *(float4*)&shift[4] = *(const float4*)(ss + 128 + c * 8 + 4);
    }

    const int begin = offsets[node], end = offsets[node + 1];
    const int deg = end - begin;
    const int lo = begin + ((deg * g) >> 2);
    const int hi = begin + ((deg * (g + 1)) >> 2);

    float acc[8];
    if (g == 0) {  // self loop, counted once
        const f16* srow = (MODE == 0) ? (hprev + (size_t)x[node] * D)
                                      : (hprev + (size_t)node * D);
        f16x8 v = *(const f16x8*)(srow + c * 8);
        if constexpr (MODE == 0) {
#pragma unroll
            for (int k = 0; k < 8; ++k) acc[k] = (float)v[k];
        } else {
#pragma unroll
            for (int k = 0; k < 8; ++k) acc[k] = fmaxf(scale[k] * (float)v[k] + shift[k], 0.f);
        }
    } else {
#pragma unroll
        for (int k = 0; k < 8; ++k) acc[k] = 0.f;
    }

    for (int j = lo; j < hi; j += 4) {
        const int n = hi - j;
        int s0 = sorted_src[j];
        int s1 = (n > 1) ? sorted_src[j + 1] : s0;
        int s2 = (n > 2) ? sorted_src[j + 2] : s0;
        int s3 = (n > 3) ? sorted_src[j + 3] : s0;
        if constexpr (MODE == 0) {
            s0 = x[s0]; s1 = x[s1]; s2 = x[s2]; s3 = x[s3];
        }
        f16x8 v0 = *(const f16x8*)(hprev + (size_t)s0 * D + c * 8);
        f16x8 v1 = *(const f16x8*)(hprev + (size_t)s1 * D + c * 8);
        f16x8 v2 = *(const f16x8*)(hprev + (size_t)s2 * D + c * 8);
        f16x8 v3 = *(const f16x8*)(hprev + (size_t)s3 * D + c * 8);
        if constexpr (MODE == 0) {
#pragma unroll
            for (int k = 0; k < 8; ++k) {
                float a = (float)v0[k];
                if (n > 1) a += (float)v1[k];
                if (n > 2) a += (float)v2[k];
                if (n > 3) a += (float)v3[k];
                acc[k] += a;
            }
        } else {
#pragma unroll
            for (int k = 0; k < 8; ++k) {
                float a = fmaxf(scale[k] * (float)v0[k] + shift[k], 0.f);
                if (n > 1) a += fmaxf(scale[k] * (float)v1[k] + shift[k], 0.f);
                if (n > 2) a += fmaxf(scale[k] * (float)v2[k] + shift[k], 0.f);
                if (n > 3) a += fmaxf(scale[k] * (float)v3[k] + shift[k], 0.f);
                acc[k] += a;
            }
        }
    }

    // sum the 4 groups (lanes sharing c)
#pragma unroll
    for (int k = 0; k < 8; ++k) {
        acc[k] += __shfl_xor(acc[k], 16, 64);
        acc[k] += __shfl_xor(acc[k], 32, 64);
    }
    if (g == 0) {
        f16x8 o;
#pragma unroll
        for (int k = 0; k < 8; ++k) o[k] = (f16)acc[k];
        *(f16x8*)(agg_h + (size_t)node * D + c * 8) = o;
    }
}

__device__ __forceinline__ void gload_lds16(const void* g, void* l) {
    __builtin_amdgcn_global_load_lds((const __attribute__((address_space(1))) void*)g,
                                     (__attribute__((address_space(3))) void*)l, 16, 0, 0);
}

// Fused GIN MLP, 16-row tile: z2 = (relu(agg @ W1 + b1)) @ W2 + b2 (f16).
// 4 waves: stage-1 each wave owns a 64-col strip of z1 (16 MFMA); stage-2 a 32-col
// strip of z2 (16 MFMA). Column stats -> global atomicAdd into partial2[blk&15][256].
__global__ __launch_bounds__(256) void fused_mlp(const f16* __restrict__ A,
                                                 const f16* __restrict__ w1f,
                                                 const float* __restrict__ b1,
                                                 const f16* __restrict__ w2f,
                                                 const float* __restrict__ b2,
                                                 f16* __restrict__ z2h,
                                                 float* __restrict__ partial2) {
    __shared__ __align__(16) char smem[8192];
    f16* As = (f16*)smem;                   // 16 x 128 halfs, swizzled (4 KB), aliased by z1s
    f16* z1s = (f16*)smem;                  // 16 x 256 halfs, swizzled (8 KB)

    const int tid = threadIdx.x;
    const int r0 = blockIdx.x * MT;
    const int lane = tid & 63;
    const int wave = tid >> 6;              // 0..3
    const int l15 = lane & 15, l4 = lane >> 4;

    // ---- stage A tile (16 x 128): one 16B gload per thread, pre-swizzled source ----
    {
        const int row = tid >> 4, c = tid & 15;
        const char* gsrc = (const char*)(A + (size_t)(r0 + row) * D) + ((c * 16) ^ ((row & 7) << 4));
        gload_lds16(gsrc, (char*)As + tid * 16);
    }
    __syncthreads();

    // ---- stage 1: z1^T via mfma(W1, A). lane holds z1[m=l15][n=wave*64+cf*16+l4*4+j] ----
    f32x4 acc1[4] = {};
#pragma unroll
    for (int kk = 0; kk < 4; ++kk) {
        const int m = l15;
        const int byte = ((m * D + kk * 32 + l4 * 8) * 2) ^ ((m & 7) << 4);
        f16x8 afr = *(const f16x8*)((const char*)As + byte);
#pragma unroll
        for (int cf = 0; cf < 4; ++cf) {
            f16x8 w = *(const f16x8*)(w1f + ((((wave * 4 + cf) * 4) + kk) * 64 + lane) * 8);
            acc1[cf] = __builtin_amdgcn_mfma_f32_16x16x32_f16(w, afr, acc1[cf], 0, 0, 0);
        }
    }
    __syncthreads();  // all As reads complete before overwriting with z1s

    // ---- epilogue 1: bias + relu -> f16 -> z1s (contiguous 8B writes, swizzled) ----
    {
        const int m = l15;
#pragma unroll
        for (int cf = 0; cf < 4; ++cf) {
            const int n = wave * 64 + cf * 16 + l4 * 4;
            const float4 bb = *(const float4*)(b1 + n);
            f16x4 v;
            v[0] = (f16)fmaxf(acc1[cf][0] + bb.x, 0.f);
            v[1] = (f16)fmaxf(acc1[cf][1] + bb.y, 0.f);
            v[2] = (f16)fmaxf(acc1[cf][2] + bb.z, 0.f);
            v[3] = (f16)fmaxf(acc1[cf][3] + bb.w, 0.f);
            const int byte = ((m * 256 + n) * 2) ^ ((m & 7) << 4);
            *(f16x4*)((char*)z1s + byte) = v;
        }
    }
    __syncthreads();

    // ---- stage 2: z2 = z1 @ W2 (non-swapped), 2 col frags per wave ----
    f32x4 acc2[2] = {};
#pragma unroll
    for (int kk = 0; kk < 8; ++kk) {
        const int m = l15;
        const int byte = ((m * 256 + kk * 32 + l4 * 8) * 2) ^ ((m & 7) << 4);
        f16x8 afr = *(const f16x8*)((const char*)z1s + byte);
#pragma unroll
        for (int cf = 0; cf < 2; ++cf) {
            f16x8 w = *(const f16x8*)(w2f + ((((wave * 2 + cf) * 8) + kk) * 64 + lane) * 8);
            acc2[cf] = __builtin_amdgcn_mfma_f32_16x16x32_f16(afr, w, acc2[cf], 0, 0, 0);
        }
    }

    // ---- epilogue 2: bias, store f16, column stats direct to global slot ----
    float bv[2];
#pragma unroll
    for (int cf = 0; cf < 2; ++cf) bv[cf] = b2[wave * 32 + cf * 16 + l15];

    float* slot = partial2 + (size_t)(blockIdx.x & (NSLOT - 1)) * 256;
    float cs[2], cq[2];
#pragma unroll
    for (int cf = 0; cf < 2; ++cf) { cs[cf] = 0.f; cq[cf] = 0.f; }
#pragma unroll
    for (int cf = 0; cf < 2; ++cf) {
        const int col = wave * 32 + cf * 16 + l15;
#pragma unroll
        for (int j = 0; j < 4; ++j) {
            const int row = r0 + l4 * 4 + j;
            if (row < N_NODES) {
                float z = acc2[cf][j] + bv[cf];
                z2h[(size_t)row * D + col] = (f16)z;
                cs[cf] += z;
                cq[cf] += z * z;
            }
        }
    }
#pragma unroll
    for (int cf = 0; cf < 2; ++cf) {
        float s = cs[cf], q = cq[cf];
        s += __shfl_xor(s, 16, 64);
        q += __shfl_xor(q, 16, 64);
        s += __shfl_xor(s, 32, 64);
        q += __shfl_xor(q, 32, 64);
        if (l4 == 0) {
            const int col = wave * 32 + cf * 16 + l15;
            atomicAdd(&slot[col], s);
            atomicAdd(&slot[D + col], q);
        }
    }
}

// finish stats from the 16 slots (1024 threads: thread (q,c) sums 4 slots), emit BN
// affine (ss[c]=scale, ss[128+c]=shift), zero the slots behind itself.
__global__ __launch_bounds__(1024) void reduce2_kernel(float* __restrict__ partial2,
                                                       const float* __restrict__ gamma,
                                                       const float* __restrict__ beta,
                                                       float* __restrict__ ss) {
    __shared__ float st[4][256];
    const int c = threadIdx.x & 255, q = threadIdx.x >> 8;
    float s = 0.f;
#pragma unroll
    for (int r = 0; r < 4; ++r) {
        s += partial2[(size_t)(q * 4 + r) * 256 + c];
        partial2[(size_t)(q * 4 + r) * 256 + c] = 0.f;
    }
    st[q][c] = s;
    __syncthreads();
    if (q == 0 && c < 128) {
        float sum = st[0][c] + st[1][c] + st[2][c] + st[3][c];
        float sq = st[0][128 + c] + st[1][128 + c] + st[2][128 + c] + st[3][128 + c];
        const float invN = 1.0f / (float)N_NODES;
        float mean = sum * invN;
        float var = sq * invN - mean * mean;
        float sc = gamma[c] * rsqrtf(var + EPS);
        ss[c] = sc;
        ss[128 + c] = beta[c] - mean * sc;
    }
}

// final-layer BN (no relu), f32 output to d_out
__global__ void bn_last_kernel(const f16* __restrict__ z, const float* __restrict__ ss,
                               float* __restrict__ hout) {
    int idx = blockIdx.x * blockDim.x + threadIdx.x;  // one 8-elem chunk
    if (idx >= N_NODES * (D / 8)) return;
    int d8 = idx & 15;
    f16x8 v = *(const f16x8*)(z + (size_t)idx * 8);
    float4 s0 = *(const float4*)(ss + d8 * 8);
    float4 s1 = *(const float4*)(ss + d8 * 8 + 4);
    float4 t0 = *(const float4*)(ss + 128 + d8 * 8);
    float4 t1 = *(const float4*)(ss + 128 + d8 * 8 + 4);
    float4 o0, o1;
    o0.x = s0.x * (float)v[0] + t0.x;
    o0.y = s0.y * (float)v[1] + t0.y;
    o0.z = s0.z * (float)v[2] + t0.z;
    o0.w = s0.w * (float)v[3] + t0.w;
    o1.x = s1.x * (float)v[4] + t1.x;
    o1.y = s1.y * (float)v[5] + t1.y;
    o1.z = s1.z * (float)v[6] + t1.z;
    o1.w = s1.w * (float)v[7] + t1.w;
    *(float4*)(hout + (size_t)idx * 8) = o0;
    *(float4*)(hout + (size_t)idx * 8 + 4) = o1;
}

extern "C" void kernel_launch(void* const* d_in, const int* in_sizes, int n_in,
                              void* d_out, int out_size, void* d_ws, size_t ws_size,
                              hipStream_t stream) {
    const int* x_nodes = (const int*)d_in[0];
    const int* src = (const int*)d_in[1];
    const int* dst = (const int*)d_in[2];
    const float* emb = (const float*)d_in[3];
    const float* W1 = (const float*)d_in[4];
    const float* b1 = (const float*)d_in[5];
    const float* W2 = (const float*)d_in[6];
    const float* b2 = (const float*)d_in[7];
    const float* gamma = (const float*)d_in[8];
    const float* beta = (const float*)d_in[9];

    float* h = (float*)d_out;  // final fp32 output

    // workspace layout: partial2 and deg contiguous so ONE memset covers both
    f16* zA = (f16*)d_ws;                                       // N*D f16 (agg_h)
    f16* zB = zA + (size_t)N_NODES * D;                         // N*D f16 (z2h)
    f16* w1f = zB + (size_t)N_NODES * D;                        // L*32768 f16
    f16* w2f = w1f + (size_t)NLAYERS * 2 * D * D;               // L*32768 f16
    f16* emb_h = w2f + (size_t)NLAYERS * 2 * D * D;             // 5*D f16 (pad to 1024)
    float* ss = (float*)(emb_h + 1024);                         // 256 f32 (scale|shift)
    float* partial2 = ss + 256;                                 // NSLOT*256 f32 (zeroed)
    int* deg = (int*)(partial2 + (size_t)NSLOT * 256);          // N (zeroed)
    int* offsets = deg + N_NODES;                               // N+1
    int* cursor = offsets + N_NODES + 1;                        // N
    int* blocksums = cursor + N_NODES;                          // 64
    int* sorted_src = blocksums + 64;                           // E

    dim3 blk(256);
    const int nb_scan = (N_NODES + 1023) / 1024;  // 49
    const int nb_edge = (N_EDGES + 255) / 256;

    // ---- one-time per call: weights + CSR ----
    convert_w_kernel<<<(NLAYERS * 32768 + 255) / 256, blk, 0, stream>>>(W1, W2, emb,
                                                                        w1f, w2f, emb_h);
    hipMemsetAsync(partial2, 0, NSLOT * 256 * sizeof(float) + N_NODES * sizeof(int), stream);
    deg_kernel<<<nb_edge, blk, 0, stream>>>(dst, deg);
    scan_block_kernel<<<nb_scan, 1024, 0, stream>>>(deg, offsets, blocksums);
    scan_add_kernel<<<nb_scan, 1024, 0, stream>>>(offsets, blocksums, cursor);
    scatter_kernel<<<nb_edge, blk, 0, stream>>>(src, dst, cursor, sorted_src);

    // ---- model: per layer {agg (fused BN+relu of prev), MLP(+atomic stats), reduce2} ----
    const int agg_gx = (N_NODES + 3) / 4;
    for (int l = 0; l < NLAYERS; ++l) {
        if (l == 0) {
            agg_kernel<0><<<agg_gx, blk, 0, stream>>>(offsets, sorted_src, emb_h,
                                                      x_nodes, nullptr, zA);
        } else {
            agg_kernel<1><<<agg_gx, blk, 0, stream>>>(offsets, sorted_src, zB,
                                                      nullptr, ss, zA);
        }
        fused_mlp<<<GX_BLOCKS, blk, 0, stream>>>(zA, w1f + (size_t)l * 32768, b1 + l * 2 * D,
                                                 w2f + (size_t)l * 32768, b2 + l * D, zB, partial2);
        reduce2_kernel<<<1, 1024, 0, stream>>>(partial2, gamma + l * D, beta + l * D, ss);
    }
    bn_last_kernel<<<(N_NODES * 16 + 255) / 256, blk, 0, stream>>>(zB, ss, h);
    (void)in_sizes; (void)n_in; (void)out_size; (void)ws_size;
}